// Round 20
// baseline (263.968 us; speedup 1.0000x reference)
//
#include <hip/hip_runtime.h>

typedef float f32x4 __attribute__((ext_vector_type(4)));
typedef float f32x16 __attribute__((ext_vector_type(16)));
typedef __bf16 bf16x8 __attribute__((ext_vector_type(8)));
typedef short s16x8 __attribute__((ext_vector_type(8)));
typedef unsigned short u16;
typedef unsigned int u32;

#define DEV static __device__ __forceinline__

constexpr int BATCH = 4;
constexpr int SQ    = 2048;
constexpr int SKV   = 2048;
constexpr int DMODEL= 512;
constexpr int NH    = 8;
constexpr int DH    = 64;
constexpr int MROWS = BATCH * SQ;      // 8192
constexpr float LN_EPS = 1e-5f;

DEV u16 f2bf(float f) {
    unsigned u = __builtin_bit_cast(unsigned, f);
    unsigned r = (u + 0x7FFFu + ((u >> 16) & 1u)) >> 16;
    return (u16)r;
}
DEV float bf2f(u16 h) { return __builtin_bit_cast(float, ((unsigned)h) << 16); }

DEV f32x4 mfma16(s16x8 a, s16x8 b, f32x4 c) {
    return __builtin_amdgcn_mfma_f32_16x16x32_bf16(
        __builtin_bit_cast(bf16x8, a), __builtin_bit_cast(bf16x8, b), c, 0, 0, 0);
}
DEV f32x16 mfma32(s16x8 a, s16x8 b, f32x16 c) {
    return __builtin_amdgcn_mfma_f32_32x32x16_bf16(
        __builtin_bit_cast(bf16x8, a), __builtin_bit_cast(bf16x8, b), c, 0, 0, 0);
}
DEV u32 cvtpk(float lo, float hi) {
    u32 r;
    asm("v_cvt_pk_bf16_f32 %0, %1, %2" : "=v"(r) : "v"(lo), "v"(hi));
    return r;
}

// ---------------------------------------------------------------------------
// LayerNorm -> bf16. One wave per row of 512. Block = 4 rows.
// ---------------------------------------------------------------------------
__global__ __launch_bounds__(256) void ln_kernel(
    const float* __restrict__ X, const float* __restrict__ G, const float* __restrict__ Bt,
    u16* __restrict__ oh)
{
    int row  = blockIdx.x * 4 + (threadIdx.x >> 6);
    int lane = threadIdx.x & 63;
    const float4* xr = (const float4*)(X + (size_t)row * DMODEL);
    float4 a = xr[lane * 2], b = xr[lane * 2 + 1];
    float vv[8] = {a.x, a.y, a.z, a.w, b.x, b.y, b.z, b.w};
    float s = 0.f;
#pragma unroll
    for (int i = 0; i < 8; i++) s += vv[i];
#pragma unroll
    for (int o = 32; o; o >>= 1) s += __shfl_xor(s, o);
    float mu = s * (1.0f / DMODEL);
    float vs = 0.f;
#pragma unroll
    for (int i = 0; i < 8; i++) { float d = vv[i] - mu; vs += d * d; }
#pragma unroll
    for (int o = 32; o; o >>= 1) vs += __shfl_xor(vs, o);
    float rstd = rsqrtf(vs * (1.0f / DMODEL) + LN_EPS);

    const float4* g4 = (const float4*)G;
    const float4* b4 = (const float4*)Bt;
    float4 g0 = g4[lane * 2], g1 = g4[lane * 2 + 1];
    float4 c0 = b4[lane * 2], c1 = b4[lane * 2 + 1];
    float gg[8] = {g0.x, g0.y, g0.z, g0.w, g1.x, g1.y, g1.z, g1.w};
    float cc[8] = {c0.x, c0.y, c0.z, c0.w, c1.x, c1.y, c1.z, c1.w};

    s16x8 vh;
#pragma unroll
    for (int i = 0; i < 8; i++) {
        float t = (vv[i] - mu) * rstd * gg[i] + cc[i];
        vh[i] = (short)f2bf(t);
    }
    *(s16x8*)(oh + (size_t)row * DMODEL + lane * 8) = vh;
}

// ---------------------------------------------------------------------------
// Weight transpose -> bf16, all 4 weights in one launch
// ---------------------------------------------------------------------------
__global__ __launch_bounds__(256) void wsplit_kernel(
    const float* __restrict__ W0, const float* __restrict__ W1,
    const float* __restrict__ W2, const float* __restrict__ W3,
    u16* __restrict__ t0)
{
    int which = blockIdx.y;
    const float* W = which == 0 ? W0 : which == 1 ? W1 : which == 2 ? W2 : W3;
    u16* th = t0 + (size_t)which * 262144;
    int idx = blockIdx.x * 256 + threadIdx.x;     // idx = n*512 + k
    int n = idx >> 9, k = idx & 511;
    th[idx] = f2bf(W[(size_t)k * 512 + n]);
}

// ---------------------------------------------------------------------------
// 1-term bf16 GEMM, 128x128 tile (ladder step-2: 4 waves, 64x64 quadrant
// each, acc[4][4]; MFMA:ds_read per kk = 2:1 vs 1:1 at 64^2).
// MODE 6: scaled bf16 out at (b,h,s,d)   (Q/K)
// MODE 5: bf16 V^T out at (b,h,d,s)       (V)
// MODE 4: fp32 + bias out                 (out)
// Fragment addressing identical to the 19-round-verified 64^2 kernel.
// ---------------------------------------------------------------------------
template<int MODE>
__global__ __launch_bounds__(256) void gemm_bf16(
    const u16* __restrict__ Ah, const u16* __restrict__ Bh,
    void* __restrict__ out0, const float* __restrict__ bias, float scl)
{
    constexpr int K  = 512;
    constexpr int LS = 72;   // padded stride (bf16 elems)
    __shared__ u16 lA[128][LS];
    __shared__ u16 lB[128][LS];

    int bm = blockIdx.x, bn = blockIdx.y;
    int tid = threadIdx.x, lane = tid & 63, wv = tid >> 6;
    int wm = (wv >> 1) * 64, wn = (wv & 1) * 64;
    int srow = tid >> 3, scol = (tid & 7) * 8;   // 32 rows x 64 cols per pass

    f32x4 acc[4][4] = {};

    for (int k0 = 0; k0 < K; k0 += 64) {
#pragma unroll
        for (int p = 0; p < 4; p++) {
            *(int4*)&lA[srow + p * 32][scol] =
                *(const int4*)(Ah + ((size_t)(bm * 128 + srow + p * 32)) * K + k0 + scol);
            *(int4*)&lB[srow + p * 32][scol] =
                *(const int4*)(Bh + ((size_t)(bn * 128 + srow + p * 32)) * K + k0 + scol);
        }
        __syncthreads();
        int fr = lane & 15, fg = (lane >> 4) * 8;
#pragma unroll
        for (int kk = 0; kk < 64; kk += 32) {
            s16x8 af[4], bf[4];
#pragma unroll
            for (int m = 0; m < 4; m++)
                af[m] = *(const s16x8*)&lA[wm + m * 16 + fr][kk + fg];
#pragma unroll
            for (int n = 0; n < 4; n++)
                bf[n] = *(const s16x8*)&lB[wn + n * 16 + fr][kk + fg];
#pragma unroll
            for (int m = 0; m < 4; m++)
#pragma unroll
                for (int n = 0; n < 4; n++)
                    acc[m][n] = mfma16(af[m], bf[n], acc[m][n]);
        }
        __syncthreads();
    }

    int fr = lane & 15, fq = lane >> 4;
#pragma unroll
    for (int m = 0; m < 4; m++)
#pragma unroll
        for (int n = 0; n < 4; n++)
#pragma unroll
            for (int r = 0; r < 4; r++) {
                int gm = bm * 128 + wm + m * 16 + fq * 4 + r;
                int gn = bn * 128 + wn + n * 16 + fr;
                float v = acc[m][n][r];
                if (MODE == 6) {
                    v *= scl;
                    int b_ = gm >> 11, s_ = gm & 2047, h_ = gn >> 6, d_ = gn & 63;
                    size_t adr = (((size_t)(b_ * NH + h_)) * SKV + s_) * DH + d_;
                    ((u16*)out0)[adr] = f2bf(v);
                } else if (MODE == 5) {
                    int b_ = gm >> 11, s_ = gm & 2047, h_ = gn >> 6, d_ = gn & 63;
                    size_t adr = (((size_t)(b_ * NH + h_)) * DH + d_) * SKV + s_;
                    ((u16*)out0)[adr] = f2bf(v);
                } else {
                    v += bias[gn];
                    ((float*)out0)[(size_t)gm * DMODEL + gn] = v;
                }
            }
}

// ---------------------------------------------------------------------------
// Streaming attention (R19 verified body, unchanged).
// One block = one 32-q-row tile, 4 waves; wave w owns kv quarter (16 tiles).
// Pass 1: rowsum of exp(S). Pass 2: K prefetched one tile ahead, normalized
// P packed to bf16 for PV, attn coalesced via per-wave LDS transpose,
// nontemporal f32x4 stores. ctx written single bf16.
//
// Layouts (mfma_f32_32x32x16_bf16, measured m74/m101):
//   A/B frag: row(col) = lane&31, k = 8*(lane>>5) + j, j=0..7
//   C:        col = lane&31,     row = (r&3) + 8*(r>>2) + 4*(lane>>5)
// NOTE: swapped QK^T => q lane-local; attn rows live ACROSS lanes => LDS
// transpose required for coalesced attn stores (round-8 lesson).
// ---------------------------------------------------------------------------
__global__ __launch_bounds__(256, 4) void attn_kernel(
    const u16* __restrict__ Qh, const u16* __restrict__ Kh,
    const u16* __restrict__ VT,
    float* __restrict__ attn, u16* __restrict__ ch)
{
    __shared__ float R[4][2112];
    __shared__ float rs[4][32];
    int tid = threadIdx.x, lane = tid & 63, wid = tid >> 6;
    int h  = lane >> 5;
    int ql = lane & 31;
    int off = 8 * h;

    // XCD-chunked bijective swizzle: 2048 blocks, 8 XCDs x 256; 4 bh per XCD
    int vb = (blockIdx.x & 7) * 256 + (blockIdx.x >> 3);
    int bh = vb >> 6;
    int qt = vb & 63;
    int q0 = qt * 32;
    const size_t base = (size_t)bh * (SKV * DH);
    int kt0 = wid * 16;

    // ---- Q B-fragments: Q[q0+ql][16c + 8h + 0..7] ----
    s16x8 qf[4];
    {
        const u16* qp = Qh + base + ((size_t)(q0 + ql)) * DH + off;
#pragma unroll
        for (int c = 0; c < 4; c++) qf[c] = *(const s16x8*)(qp + c * 16);
    }

    // ---- pass 1: partial rowsum of exp(S) ----
    float rsum0 = 0.f, rsum1 = 0.f;
    for (int kt = kt0; kt < kt0 + 16; kt++) {
        size_t kb = base + ((size_t)(kt * 32 + ql)) * DH + off;
        s16x8 kh[4];
#pragma unroll
        for (int c = 0; c < 4; c++) kh[c] = *(const s16x8*)(Kh + kb + c * 16);
        f32x16 a1 = 0;
#pragma unroll
        for (int c = 0; c < 4; c++) a1 = mfma32(kh[c], qf[c], a1);
#pragma unroll
        for (int r = 0; r < 16; r += 2) {
            rsum0 += __expf(a1[r]);
            rsum1 += __expf(a1[r + 1]);
        }
    }
    float rsum = rsum0 + rsum1;
    rsum += __shfl_xor(rsum, 32);
    if (lane < 32) rs[wid][ql] = rsum;
    __syncthreads();
    float inv_l = 1.0f / (rs[0][ql] + rs[1][ql] + rs[2][ql] + rs[3][ql]);

    // ---- pass 2: K prefetched one tile ahead; stores issued last ----
    f32x16 pv0 = 0, pv1 = 0;
    const u16* vbase = VT + (size_t)bh * (DH * SKV) + (size_t)ql * SKV + off;

    s16x8 kA[4];
    {
        size_t kb = base + ((size_t)(kt0 * 32 + ql)) * DH + off;
#pragma unroll
        for (int c = 0; c < 4; c++) kA[c] = *(const s16x8*)(Kh + kb + c * 16);
    }

    for (int i = 0; i < 16; i++) {
        int kt = kt0 + i;
        // --- issue this tile's V loads early (before any stores this body) ---
        const u16* vp = vbase + kt * 32;
        s16x8 v00 = *(const s16x8*)(vp);
        s16x8 v01 = *(const s16x8*)(vp + 16);
        s16x8 v10 = *(const s16x8*)(vp + (size_t)32 * SKV);
        s16x8 v11 = *(const s16x8*)(vp + (size_t)32 * SKV + 16);
        // --- issue next tile's K prefetch ---
        s16x8 kB[4];
        if (i + 1 < 16) {
            size_t kb = base + ((size_t)((kt + 1) * 32 + ql)) * DH + off;
#pragma unroll
            for (int c = 0; c < 4; c++) kB[c] = *(const s16x8*)(Kh + kb + c * 16);
        }
        // --- QK^T from prefetched regs ---
        f32x16 acc = 0;
#pragma unroll
        for (int c = 0; c < 4; c++) acc = mfma32(kA[c], qf[c], acc);
#pragma unroll
        for (int r = 0; r < 16; r++) acc[r] = __expf(acc[r]) * inv_l;

        // --- PV: pack to bf16 + permlane -> B-frags ---
        u32 O0[4], O1[4];
#pragma unroll
        for (int g = 0; g < 4; g++) {
            O0[g] = cvtpk(acc[4 * g + 0], acc[4 * g + 1]);
            O1[g] = cvtpk(acc[4 * g + 2], acc[4 * g + 3]);
        }
        {
            u32 a = O0[0], b = O0[1], c = O1[0], d = O1[1];
            asm("v_permlane32_swap_b32 %0, %1" : "+v"(a), "+v"(b));
            asm("v_permlane32_swap_b32 %0, %1" : "+v"(c), "+v"(d));
            uint4 w = {a, c, b, d};
            s16x8 bf = __builtin_bit_cast(s16x8, w);
            pv0 = mfma32(v00, bf, pv0);
            pv1 = mfma32(v10, bf, pv1);
        }
        {
            u32 a = O0[2], b = O0[3], c = O1[2], d = O1[3];
            asm("v_permlane32_swap_b32 %0, %1" : "+v"(a), "+v"(b));
            asm("v_permlane32_swap_b32 %0, %1" : "+v"(c), "+v"(d));
            uint4 w = {a, c, b, d};
            s16x8 bf = __builtin_bit_cast(s16x8, w);
            pv0 = mfma32(v01, bf, pv0);
            pv1 = mfma32(v11, bf, pv1);
        }

        // --- LDS transpose (double-buffered by parity) ---
        float* buf = &R[wid][(i & 1) * 1056];
#pragma unroll
        for (int r = 0; r < 16; r++)
            buf[ql * 33 + (r & 3) + 8 * (r >> 2) + 4 * h] = acc[r];

        // --- attn burst: nontemporal, issued last in the body ---
#pragma unroll
        for (int p = 0; p < 4; p++) {
            int q = p * 8 + (lane >> 3), j4 = (lane & 7) * 4;
            f32x4 o;
            o.x = buf[q * 33 + j4 + 0];
            o.y = buf[q * 33 + j4 + 1];
            o.z = buf[q * 33 + j4 + 2];
            o.w = buf[q * 33 + j4 + 3];
            __builtin_nontemporal_store(o,
                (f32x4*)&attn[((size_t)(bh * SQ + q0 + q)) * SKV + kt * 32 + j4]);
        }

#pragma unroll
        for (int c = 0; c < 4; c++) kA[c] = kB[c];
    }

    // ---- write PV partials to own LDS region ----
#pragma unroll
    for (int r = 0; r < 16; r++) {
        R[wid][r * 64 + lane]        = pv0[r];
        R[wid][1024 + r * 64 + lane] = pv1[r];
    }
    __syncthreads();

    // ---- waves 0,1 reduce 4 partials for d-half X=wid; ctx single bf16 ----
    if (wid < 2) {
        int X = wid;
        float s[16];
#pragma unroll
        for (int r = 0; r < 16; r++)
            s[r] = R[0][X * 1024 + r * 64 + lane] + R[1][X * 1024 + r * 64 + lane]
                 + R[2][X * 1024 + r * 64 + lane] + R[3][X * 1024 + r * 64 + lane];
        int b_ = bh >> 3, hh = bh & 7;
        size_t rowa = ((size_t)(b_ * SQ + q0 + ql)) * DMODEL + hh * 64 + X * 32 + 4 * h;
#pragma unroll
        for (int g = 0; g < 4; g++) {
            u16 hv[4];
#pragma unroll
            for (int i = 0; i < 4; i++) hv[i] = f2bf(s[4 * g + i]);
            *(ushort4*)(ch + rowa + 8 * g) = *(ushort4*)hv;
        }
    }
}

// ---------------------------------------------------------------------------
extern "C" void kernel_launch(void* const* d_in, const int* in_sizes, int n_in,
                              void* d_out, int out_size, void* d_ws, size_t ws_size,
                              hipStream_t stream)
{
    const float* x   = (const float*)d_in[0];
    const float* y   = (const float*)d_in[1];
    const float* lqg = (const float*)d_in[2];
    const float* lqb = (const float*)d_in[3];
    const float* lkg = (const float*)d_in[4];
    const float* lkb = (const float*)d_in[5];
    const float* Wq  = (const float*)d_in[6];
    const float* Wk  = (const float*)d_in[7];
    const float* Wv  = (const float*)d_in[8];
    const float* Wo  = (const float*)d_in[9];
    const float* bo  = (const float*)d_in[10];

    char* ws = (char*)d_ws;
    size_t off = 0;
    auto alloc = [&](size_t nelem) -> u16* {
        u16* p = (u16*)(ws + off);
        off += (nelem * 2 + 255) & ~(size_t)255;
        return p;
    };
    const size_t NROW = (size_t)MROWS * DMODEL;
    u16* xnh = alloc(NROW);
    u16* ynh = alloc(NROW);
    u16* wbase = alloc(4 * 262144);
    u16* wqh = wbase + 0 * 262144;
    u16* wkh = wbase + 1 * 262144;
    u16* wvh = wbase + 2 * 262144;
    u16* woh = wbase + 3 * 262144;
    u16* qh_ = alloc(NROW);
    u16* kh_ = alloc(NROW);
    u16* vt_ = alloc(NROW);
    u16* ct_ = alloc(NROW);

    float* outp  = (float*)d_out;
    float* attnp = outp + (size_t)MROWS * DMODEL;

    ln_kernel<<<MROWS / 4, 256, 0, stream>>>(x, lqg, lqb, xnh);
    ln_kernel<<<MROWS / 4, 256, 0, stream>>>(y, lkg, lkb, ynh);
    wsplit_kernel<<<dim3(1024, 4), 256, 0, stream>>>(Wq, Wk, Wv, Wo, wbase);

    dim3 gg(MROWS / 128, 512 / 128);
    gemm_bf16<6><<<gg, 256, 0, stream>>>(xnh, wqh, qh_, nullptr, 0.125f);
    gemm_bf16<6><<<gg, 256, 0, stream>>>(ynh, wkh, kh_, nullptr, 1.0f);
    gemm_bf16<5><<<gg, 256, 0, stream>>>(ynh, wvh, vt_, nullptr, 1.0f);

    attn_kernel<<<2048, 256, 0, stream>>>(qh_, kh_, vt_, attnp, ct_);

    gemm_bf16<4><<<gg, 256, 0, stream>>>(ct_, woh, (void*)outp, bo, 1.0f);
}

// Round 22
// 254.615 us; speedup vs baseline: 1.0367x; 1.0367x over previous
//
#include <hip/hip_runtime.h>

typedef float f32x4 __attribute__((ext_vector_type(4)));
typedef float f32x16 __attribute__((ext_vector_type(16)));
typedef __bf16 bf16x8 __attribute__((ext_vector_type(8)));
typedef short s16x8 __attribute__((ext_vector_type(8)));
typedef unsigned short u16;
typedef unsigned int u32;

#define DEV static __device__ __forceinline__

constexpr int BATCH = 4;
constexpr int SQ    = 2048;
constexpr int SKV   = 2048;
constexpr int DMODEL= 512;
constexpr int NH    = 8;
constexpr int DH    = 64;
constexpr int MROWS = BATCH * SQ;      // 8192
constexpr float LN_EPS = 1e-5f;
constexpr float LOG2E  = 1.44269504088896340736f;

DEV u16 f2bf(float f) {
    unsigned u = __builtin_bit_cast(unsigned, f);
    unsigned r = (u + 0x7FFFu + ((u >> 16) & 1u)) >> 16;
    return (u16)r;
}
DEV float bf2f(u16 h) { return __builtin_bit_cast(float, ((unsigned)h) << 16); }
DEV float exp2fast(float x) { return __builtin_amdgcn_exp2f(x); }   // v_exp_f32 (natively 2^x)

DEV f32x4 mfma16(s16x8 a, s16x8 b, f32x4 c) {
    return __builtin_amdgcn_mfma_f32_16x16x32_bf16(
        __builtin_bit_cast(bf16x8, a), __builtin_bit_cast(bf16x8, b), c, 0, 0, 0);
}
DEV f32x16 mfma32(s16x8 a, s16x8 b, f32x16 c) {
    return __builtin_amdgcn_mfma_f32_32x32x16_bf16(
        __builtin_bit_cast(bf16x8, a), __builtin_bit_cast(bf16x8, b), c, 0, 0, 0);
}
DEV u32 cvtpk(float lo, float hi) {
    u32 r;
    asm("v_cvt_pk_bf16_f32 %0, %1, %2" : "=v"(r) : "v"(lo), "v"(hi));
    return r;
}

// ---------------------------------------------------------------------------
// LayerNorm -> bf16. One wave per row of 512. Block = 4 rows.
// ---------------------------------------------------------------------------
__global__ __launch_bounds__(256) void ln_kernel(
    const float* __restrict__ X, const float* __restrict__ G, const float* __restrict__ Bt,
    u16* __restrict__ oh)
{
    int row  = blockIdx.x * 4 + (threadIdx.x >> 6);
    int lane = threadIdx.x & 63;
    const float4* xr = (const float4*)(X + (size_t)row * DMODEL);
    float4 a = xr[lane * 2], b = xr[lane * 2 + 1];
    float vv[8] = {a.x, a.y, a.z, a.w, b.x, b.y, b.z, b.w};
    float s = 0.f;
#pragma unroll
    for (int i = 0; i < 8; i++) s += vv[i];
#pragma unroll
    for (int o = 32; o; o >>= 1) s += __shfl_xor(s, o);
    float mu = s * (1.0f / DMODEL);
    float vs = 0.f;
#pragma unroll
    for (int i = 0; i < 8; i++) { float d = vv[i] - mu; vs += d * d; }
#pragma unroll
    for (int o = 32; o; o >>= 1) vs += __shfl_xor(vs, o);
    float rstd = rsqrtf(vs * (1.0f / DMODEL) + LN_EPS);

    const float4* g4 = (const float4*)G;
    const float4* b4 = (const float4*)Bt;
    float4 g0 = g4[lane * 2], g1 = g4[lane * 2 + 1];
    float4 c0 = b4[lane * 2], c1 = b4[lane * 2 + 1];
    float gg[8] = {g0.x, g0.y, g0.z, g0.w, g1.x, g1.y, g1.z, g1.w};
    float cc[8] = {c0.x, c0.y, c0.z, c0.w, c1.x, c1.y, c1.z, c1.w};

    s16x8 vh;
#pragma unroll
    for (int i = 0; i < 8; i++) {
        float t = (vv[i] - mu) * rstd * gg[i] + cc[i];
        vh[i] = (short)f2bf(t);
    }
    *(s16x8*)(oh + (size_t)row * DMODEL + lane * 8) = vh;
}

// ---------------------------------------------------------------------------
// Weight transpose -> bf16, all 4 weights in one launch
// ---------------------------------------------------------------------------
__global__ __launch_bounds__(256) void wsplit_kernel(
    const float* __restrict__ W0, const float* __restrict__ W1,
    const float* __restrict__ W2, const float* __restrict__ W3,
    u16* __restrict__ t0)
{
    int which = blockIdx.y;
    const float* W = which == 0 ? W0 : which == 1 ? W1 : which == 2 ? W2 : W3;
    u16* th = t0 + (size_t)which * 262144;
    int idx = blockIdx.x * 256 + threadIdx.x;     // idx = n*512 + k
    int n = idx >> 9, k = idx & 511;
    th[idx] = f2bf(W[(size_t)k * 512 + n]);
}

// ---------------------------------------------------------------------------
// 1-term bf16 GEMM, 64x64 tile (R19-verified).
// MODE 6: scaled bf16 out at (b,h,s,d)   (Q; scl folds 0.125*log2e)
// MODE 4: fp32 + bias out                 (out)
// ---------------------------------------------------------------------------
template<int MODE>
__global__ __launch_bounds__(256) void gemm_bf16(
    const u16* __restrict__ Ah, const u16* __restrict__ Bh,
    void* __restrict__ out0, const float* __restrict__ bias, float scl)
{
    constexpr int K  = 512;
    constexpr int LS = 72;
    __shared__ u16 lA[64][LS];
    __shared__ u16 lB[64][LS];

    int bm = blockIdx.x, bn = blockIdx.y;
    int tid = threadIdx.x, lane = tid & 63, wv = tid >> 6;
    int wm = (wv >> 1) * 32, wn = (wv & 1) * 32;
    int srow = tid >> 3, scol = (tid & 7) * 8;
    const size_t aoff0 = ((size_t)(bm * 64 + srow)) * K + scol;
    const size_t aoff1 = ((size_t)(bm * 64 + srow + 32)) * K + scol;
    const size_t boff0 = ((size_t)(bn * 64 + srow)) * K + scol;
    const size_t boff1 = ((size_t)(bn * 64 + srow + 32)) * K + scol;

    f32x4 acc[2][2] = {};

    for (int k0 = 0; k0 < K; k0 += 64) {
        *(int4*)&lA[srow][scol]      = *(const int4*)(Ah + aoff0 + k0);
        *(int4*)&lA[srow + 32][scol] = *(const int4*)(Ah + aoff1 + k0);
        *(int4*)&lB[srow][scol]      = *(const int4*)(Bh + boff0 + k0);
        *(int4*)&lB[srow + 32][scol] = *(const int4*)(Bh + boff1 + k0);
        __syncthreads();
        int fr = lane & 15, fg = (lane >> 4) * 8;
#pragma unroll
        for (int kk = 0; kk < 64; kk += 32) {
            s16x8 ah[2], bh[2];
#pragma unroll
            for (int m_ = 0; m_ < 2; m_++)
                ah[m_] = *(const s16x8*)&lA[wm + m_ * 16 + fr][kk + fg];
#pragma unroll
            for (int n_ = 0; n_ < 2; n_++)
                bh[n_] = *(const s16x8*)&lB[wn + n_ * 16 + fr][kk + fg];
#pragma unroll
            for (int m_ = 0; m_ < 2; m_++)
#pragma unroll
                for (int n_ = 0; n_ < 2; n_++)
                    acc[m_][n_] = mfma16(ah[m_], bh[n_], acc[m_][n_]);
        }
        __syncthreads();
    }

    int fr = lane & 15, fq = lane >> 4;
#pragma unroll
    for (int m_ = 0; m_ < 2; m_++)
#pragma unroll
        for (int n_ = 0; n_ < 2; n_++)
#pragma unroll
            for (int r = 0; r < 4; r++) {
                int gm = bm * 64 + wm + m_ * 16 + fq * 4 + r;
                int gn = bn * 64 + wn + n_ * 16 + fr;
                float v = acc[m_][n_][r];
                if (MODE == 6) {
                    v *= scl;
                    int b_ = gm >> 11, s_ = gm & 2047, h_ = gn >> 6, d_ = gn & 63;
                    size_t adr = (((size_t)(b_ * NH + h_)) * SKV + s_) * DH + d_;
                    ((u16*)out0)[adr] = f2bf(v);
                } else {
                    v += bias[gn];
                    ((float*)out0)[(size_t)gm * DMODEL + gn] = v;
                }
            }
}

// ---------------------------------------------------------------------------
// Fused K+V GEMM: A = yn staged ONCE, two B tiles (Wk, Wv), two acc sets.
// K -> bf16 at (b,h,s,d); V -> bf16 V^T at (b,h,d,s).
// ---------------------------------------------------------------------------
__global__ __launch_bounds__(256) void gemm_kv(
    const u16* __restrict__ Ah, const u16* __restrict__ Bk, const u16* __restrict__ Bv,
    u16* __restrict__ outK, u16* __restrict__ outVT)
{
    constexpr int K  = 512;
    constexpr int LS = 72;
    __shared__ u16 lA[64][LS];
    __shared__ u16 lK[64][LS];
    __shared__ u16 lV[64][LS];

    int bm = blockIdx.x, bn = blockIdx.y;
    int tid = threadIdx.x, lane = tid & 63, wv = tid >> 6;
    int wm = (wv >> 1) * 32, wn = (wv & 1) * 32;
    int srow = tid >> 3, scol = (tid & 7) * 8;
    const size_t aoff0 = ((size_t)(bm * 64 + srow)) * K + scol;
    const size_t aoff1 = ((size_t)(bm * 64 + srow + 32)) * K + scol;
    const size_t boff0 = ((size_t)(bn * 64 + srow)) * K + scol;
    const size_t boff1 = ((size_t)(bn * 64 + srow + 32)) * K + scol;

    f32x4 ak[2][2] = {}, av[2][2] = {};

    for (int k0 = 0; k0 < K; k0 += 64) {
        *(int4*)&lA[srow][scol]      = *(const int4*)(Ah + aoff0 + k0);
        *(int4*)&lA[srow + 32][scol] = *(const int4*)(Ah + aoff1 + k0);
        *(int4*)&lK[srow][scol]      = *(const int4*)(Bk + boff0 + k0);
        *(int4*)&lK[srow + 32][scol] = *(const int4*)(Bk + boff1 + k0);
        *(int4*)&lV[srow][scol]      = *(const int4*)(Bv + boff0 + k0);
        *(int4*)&lV[srow + 32][scol] = *(const int4*)(Bv + boff1 + k0);
        __syncthreads();
        int fr = lane & 15, fg = (lane >> 4) * 8;
#pragma unroll
        for (int kk = 0; kk < 64; kk += 32) {
            s16x8 af[2], bk[2], bv[2];
#pragma unroll
            for (int m_ = 0; m_ < 2; m_++)
                af[m_] = *(const s16x8*)&lA[wm + m_ * 16 + fr][kk + fg];
#pragma unroll
            for (int n_ = 0; n_ < 2; n_++) {
                bk[n_] = *(const s16x8*)&lK[wn + n_ * 16 + fr][kk + fg];
                bv[n_] = *(const s16x8*)&lV[wn + n_ * 16 + fr][kk + fg];
            }
#pragma unroll
            for (int m_ = 0; m_ < 2; m_++)
#pragma unroll
                for (int n_ = 0; n_ < 2; n_++) {
                    ak[m_][n_] = mfma16(af[m_], bk[n_], ak[m_][n_]);
                    av[m_][n_] = mfma16(af[m_], bv[n_], av[m_][n_]);
                }
        }
        __syncthreads();
    }

    int fr = lane & 15, fq = lane >> 4;
#pragma unroll
    for (int m_ = 0; m_ < 2; m_++)
#pragma unroll
        for (int n_ = 0; n_ < 2; n_++)
#pragma unroll
            for (int r = 0; r < 4; r++) {
                int gm = bm * 64 + wm + m_ * 16 + fq * 4 + r;
                int gn = bn * 64 + wn + n_ * 16 + fr;
                int b_ = gm >> 11, s_ = gm & 2047, h_ = gn >> 6, d_ = gn & 63;
                size_t adrK = (((size_t)(b_ * NH + h_)) * SKV + s_) * DH + d_;
                size_t adrV = (((size_t)(b_ * NH + h_)) * DH + d_) * SKV + s_;
                outK[adrK]  = f2bf(ak[m_][n_][r]);
                outVT[adrV] = f2bf(av[m_][n_][r]);
            }
}

// ---------------------------------------------------------------------------
// Streaming attention (R19 verified body; exp via v_exp_f32 2^x, log2e folded
// into Q's projection scale).
// One block = one 32-q-row tile, 4 waves; wave w owns kv quarter (16 tiles).
//
// Layouts (mfma_f32_32x32x16_bf16, measured m74/m101):
//   A/B frag: row(col) = lane&31, k = 8*(lane>>5) + j, j=0..7
//   C:        col = lane&31,     row = (r&3) + 8*(r>>2) + 4*(lane>>5)
// NOTE: swapped QK^T => q lane-local; attn rows live ACROSS lanes => LDS
// transpose required for coalesced attn stores (round-8 lesson).
// ---------------------------------------------------------------------------
__global__ __launch_bounds__(256, 4) void attn_kernel(
    const u16* __restrict__ Qh, const u16* __restrict__ Kh,
    const u16* __restrict__ VT,
    float* __restrict__ attn, u16* __restrict__ ch)
{
    __shared__ float R[4][2112];
    __shared__ float rs[4][32];
    int tid = threadIdx.x, lane = tid & 63, wid = tid >> 6;
    int h  = lane >> 5;
    int ql = lane & 31;
    int off = 8 * h;

    // XCD-chunked bijective swizzle: 2048 blocks, 8 XCDs x 256; 4 bh per XCD
    int vb = (blockIdx.x & 7) * 256 + (blockIdx.x >> 3);
    int bh = vb >> 6;
    int qt = vb & 63;
    int q0 = qt * 32;
    const size_t base = (size_t)bh * (SKV * DH);
    int kt0 = wid * 16;

    // ---- Q B-fragments: Q[q0+ql][16c + 8h + 0..7] ----
    s16x8 qf[4];
    {
        const u16* qp = Qh + base + ((size_t)(q0 + ql)) * DH + off;
#pragma unroll
        for (int c = 0; c < 4; c++) qf[c] = *(const s16x8*)(qp + c * 16);
    }

    // ---- pass 1: partial rowsum of 2^(S') ----
    float rsum0 = 0.f, rsum1 = 0.f;
    for (int kt = kt0; kt < kt0 + 16; kt++) {
        size_t kb = base + ((size_t)(kt * 32 + ql)) * DH + off;
        s16x8 kh[4];
#pragma unroll
        for (int c = 0; c < 4; c++) kh[c] = *(const s16x8*)(Kh + kb + c * 16);
        f32x16 a1 = 0;
#pragma unroll
        for (int c = 0; c < 4; c++) a1 = mfma32(kh[c], qf[c], a1);
#pragma unroll
        for (int r = 0; r < 16; r += 2) {
            rsum0 += exp2fast(a1[r]);
            rsum1 += exp2fast(a1[r + 1]);
        }
    }
    float rsum = rsum0 + rsum1;
    rsum += __shfl_xor(rsum, 32);
    if (lane < 32) rs[wid][ql] = rsum;
    __syncthreads();
    float inv_l = 1.0f / (rs[0][ql] + rs[1][ql] + rs[2][ql] + rs[3][ql]);

    // ---- pass 2: K prefetched one tile ahead; stores issued last ----
    f32x16 pv0 = 0, pv1 = 0;
    const u16* vbase = VT + (size_t)bh * (DH * SKV) + (size_t)ql * SKV + off;

    s16x8 kA[4];
    {
        size_t kb = base + ((size_t)(kt0 * 32 + ql)) * DH + off;
#pragma unroll
        for (int c = 0; c < 4; c++) kA[c] = *(const s16x8*)(Kh + kb + c * 16);
    }

    for (int i = 0; i < 16; i++) {
        int kt = kt0 + i;
        // --- issue this tile's V loads early (before any stores this body) ---
        const u16* vp = vbase + kt * 32;
        s16x8 v00 = *(const s16x8*)(vp);
        s16x8 v01 = *(const s16x8*)(vp + 16);
        s16x8 v10 = *(const s16x8*)(vp + (size_t)32 * SKV);
        s16x8 v11 = *(const s16x8*)(vp + (size_t)32 * SKV + 16);
        // --- issue next tile's K prefetch ---
        s16x8 kB[4];
        if (i + 1 < 16) {
            size_t kb = base + ((size_t)((kt + 1) * 32 + ql)) * DH + off;
#pragma unroll
            for (int c = 0; c < 4; c++) kB[c] = *(const s16x8*)(Kh + kb + c * 16);
        }
        // --- QK^T from prefetched regs ---
        f32x16 acc = 0;
#pragma unroll
        for (int c = 0; c < 4; c++) acc = mfma32(kA[c], qf[c], acc);
#pragma unroll
        for (int r = 0; r < 16; r++) acc[r] = exp2fast(acc[r]) * inv_l;

        // --- PV: pack to bf16 + permlane -> B-frags ---
        u32 O0[4], O1[4];
#pragma unroll
        for (int g = 0; g < 4; g++) {
            O0[g] = cvtpk(acc[4 * g + 0], acc[4 * g + 1]);
            O1[g] = cvtpk(acc[4 * g + 2], acc[4 * g + 3]);
        }
        {
            u32 a = O0[0], b = O0[1], c = O1[0], d = O1[1];
            asm("v_permlane32_swap_b32 %0, %1" : "+v"(a), "+v"(b));
            asm("v_permlane32_swap_b32 %0, %1" : "+v"(c), "+v"(d));
            uint4 w = {a, c, b, d};
            s16x8 bf = __builtin_bit_cast(s16x8, w);
            pv0 = mfma32(v00, bf, pv0);
            pv1 = mfma32(v10, bf, pv1);
        }
        {
            u32 a = O0[2], b = O0[3], c = O1[2], d = O1[3];
            asm("v_permlane32_swap_b32 %0, %1" : "+v"(a), "+v"(b));
            asm("v_permlane32_swap_b32 %0, %1" : "+v"(c), "+v"(d));
            uint4 w = {a, c, b, d};
            s16x8 bf = __builtin_bit_cast(s16x8, w);
            pv0 = mfma32(v01, bf, pv0);
            pv1 = mfma32(v11, bf, pv1);
        }

        // --- LDS transpose (double-buffered by parity) ---
        float* buf = &R[wid][(i & 1) * 1056];
#pragma unroll
        for (int r = 0; r < 16; r++)
            buf[ql * 33 + (r & 3) + 8 * (r >> 2) + 4 * h] = acc[r];

        // --- attn burst: nontemporal, issued last in the body ---
#pragma unroll
        for (int p = 0; p < 4; p++) {
            int q = p * 8 + (lane >> 3), j4 = (lane & 7) * 4;
            f32x4 o;
            o.x = buf[q * 33 + j4 + 0];
            o.y = buf[q * 33 + j4 + 1];
            o.z = buf[q * 33 + j4 + 2];
            o.w = buf[q * 33 + j4 + 3];
            __builtin_nontemporal_store(o,
                (f32x4*)&attn[((size_t)(bh * SQ + q0 + q)) * SKV + kt * 32 + j4]);
        }

#pragma unroll
        for (int c = 0; c < 4; c++) kA[c] = kB[c];
    }

    // ---- write PV partials to own LDS region ----
#pragma unroll
    for (int r = 0; r < 16; r++) {
        R[wid][r * 64 + lane]        = pv0[r];
        R[wid][1024 + r * 64 + lane] = pv1[r];
    }
    __syncthreads();

    // ---- waves 0,1 reduce 4 partials for d-half X=wid; ctx single bf16 ----
    if (wid < 2) {
        int X = wid;
        float s[16];
#pragma unroll
        for (int r = 0; r < 16; r++)
            s[r] = R[0][X * 1024 + r * 64 + lane] + R[1][X * 1024 + r * 64 + lane]
                 + R[2][X * 1024 + r * 64 + lane] + R[3][X * 1024 + r * 64 + lane];
        int b_ = bh >> 3, hh = bh & 7;
        size_t rowa = ((size_t)(b_ * SQ + q0 + ql)) * DMODEL + hh * 64 + X * 32 + 4 * h;
#pragma unroll
        for (int g = 0; g < 4; g++) {
            u16 hv[4];
#pragma unroll
            for (int i = 0; i < 4; i++) hv[i] = f2bf(s[4 * g + i]);
            *(ushort4*)(ch + rowa + 8 * g) = *(ushort4*)hv;
        }
    }
}

// ---------------------------------------------------------------------------
extern "C" void kernel_launch(void* const* d_in, const int* in_sizes, int n_in,
                              void* d_out, int out_size, void* d_ws, size_t ws_size,
                              hipStream_t stream)
{
    const float* x   = (const float*)d_in[0];
    const float* y   = (const float*)d_in[1];
    const float* lqg = (const float*)d_in[2];
    const float* lqb = (const float*)d_in[3];
    const float* lkg = (const float*)d_in[4];
    const float* lkb = (const float*)d_in[5];
    const float* Wq  = (const float*)d_in[6];
    const float* Wk  = (const float*)d_in[7];
    const float* Wv  = (const float*)d_in[8];
    const float* Wo  = (const float*)d_in[9];
    const float* bo  = (const float*)d_in[10];

    char* ws = (char*)d_ws;
    size_t off = 0;
    auto alloc = [&](size_t nelem) -> u16* {
        u16* p = (u16*)(ws + off);
        off += (nelem * 2 + 255) & ~(size_t)255;
        return p;
    };
    const size_t NROW = (size_t)MROWS * DMODEL;
    u16* xnh = alloc(NROW);
    u16* ynh = alloc(NROW);
    u16* wbase = alloc(4 * 262144);
    u16* wqh = wbase + 0 * 262144;
    u16* wkh = wbase + 1 * 262144;
    u16* wvh = wbase + 2 * 262144;
    u16* woh = wbase + 3 * 262144;
    u16* qh_ = alloc(NROW);
    u16* kh_ = alloc(NROW);
    u16* vt_ = alloc(NROW);
    u16* ct_ = alloc(NROW);

    float* outp  = (float*)d_out;
    float* attnp = outp + (size_t)MROWS * DMODEL;

    ln_kernel<<<MROWS / 4, 256, 0, stream>>>(x, lqg, lqb, xnh);
    ln_kernel<<<MROWS / 4, 256, 0, stream>>>(y, lkg, lkb, ynh);
    wsplit_kernel<<<dim3(1024, 4), 256, 0, stream>>>(Wq, Wk, Wv, Wo, wbase);

    dim3 gg(MROWS / 64, 512 / 64);
    gemm_bf16<6><<<gg, 256, 0, stream>>>(xnh, wqh, qh_, nullptr, 0.125f * LOG2E);
    gemm_kv<<<gg, 256, 0, stream>>>(ynh, wkh, wvh, kh_, vt_);

    attn_kernel<<<2048, 256, 0, stream>>>(qh_, kh_, vt_, attnp, ct_);

    gemm_bf16<4><<<gg, 256, 0, stream>>>(ct_, woh, (void*)outp, bo, 1.0f);
}